// Round 4
// baseline (12553.123 us; speedup 1.0000x reference)
//
#include <hip/hip_runtime.h>
#include <math.h>

// Problem dims
#define NB 16
#define NP 196
#define NE 1024
#define ND 512
#define NEMB 512
#define NV 10000
#define NL 32
#define NT 31
#define NG 2048  // 4*D

#define NBLK 256   // cooperative grid == CU count (proven-safe)

// d_out float offsets (real outputs)
#define OFF_PRED    0
#define OFF_CAPS    4960000
#define OFF_DECLEN  4960512
#define OFF_ALPHAS  4960528
#define OFF_SORTIND 5057744

// d_out-aliased scratch (floats; all dead before fc GEMM overwrites pred region)
#define OFF_ATT1B   0         // ushort[3136*1024]          -> 1,605,632 floats
#define OFF_PREIHB  1605632   // ushort[496*2048]           ->   507,904 floats
#define OFF_ENCT    2113536   // ushort[16*1024*208]        -> 1,703,936 floats (end 3,817,472)

// Workspace float offsets (total 254,016 floats = 1.02 MB, under proven 1.49 MB)
#define WS_BAR    32         // 2 uints (cnt, gen), init by k_sort
#define WS_H      64
#define WS_C      8256
#define WS_M1     16448      // [16][4096] fp32: att2 | gateS | gates_h  (also k_mean scratch)
#define WS_GSUM   81984      // [16][2048] fp32
#define WS_SCORES 114752     // [16][256] fp32
#define WS_AWEG   118848     // ushort[16*1024] (8192 floats)
#define WS_HHIST  127040     // ushort[31*16*512] (126,976 floats) -> end 254,016

__device__ __forceinline__ float sigf(float x){ return 1.0f/(1.0f+expf(-x)); }
__device__ __forceinline__ unsigned short bf16rne(float x){
  unsigned u = __float_as_uint(x);
  unsigned r = (u + 0x7fffu + ((u>>16)&1u)) >> 16;
  return (unsigned short)r;
}
__device__ __forceinline__ float bf2f(unsigned short h){ return __uint_as_float(((unsigned)h)<<16); }
__device__ __forceinline__ void u2f2(unsigned u, float&a, float&b){
  a = __uint_as_float(u<<16); b = __uint_as_float(u & 0xffff0000u);
}

// ---------------- sort + small outputs + barrier init ----------------
__global__ void k_sort(const int* __restrict__ caplen, const int* __restrict__ caps,
                       int* __restrict__ wsi, float* __restrict__ out){
  __shared__ int sidx[NB];
  int tid = threadIdx.x;
  if (tid == 0){
    int len[NB], idx[NB];
    for (int i=0;i<NB;i++){ len[i]=caplen[i]; idx[i]=i; }
    for (int i=1;i<NB;i++){
      int key=idx[i]; int kl=len[key]; int j=i-1;
      while (j>=0 && len[idx[j]]<kl){ idx[j+1]=idx[j]; j--; }
      idx[j+1]=key;
    }
    for (int b=0;b<NB;b++){
      sidx[b]=idx[b];
      wsi[b]=idx[b];
      int dl = len[idx[b]]-1;
      wsi[NB+b]=dl;
      out[OFF_DECLEN+b]=(float)dl;
      out[OFF_SORTIND+b]=(float)idx[b];
    }
    ((unsigned*)wsi)[WS_BAR]   = 0u;   // barrier count
    ((unsigned*)wsi)[WS_BAR+1] = 0u;   // barrier generation
  }
  __syncthreads();
  for (int x=tid; x<NB*NL; x+=blockDim.x){
    int b = x>>5, l = x&31;
    out[OFF_CAPS + x] = (float)caps[sidx[b]*NL + l];
  }
}

// ---------------- mean over P (scratch in WS_M1 region) ----------------
__global__ __launch_bounds__(256) void k_mean(const float* __restrict__ enc,
                                              const int* __restrict__ wsi,
                                              float* __restrict__ wsf){
  int gid = blockIdx.x*256 + threadIdx.x;   // 16384 = 16*1024
  int b = gid>>10, e = gid&1023;
  int ob = wsi[b];
  const float* p = enc + (size_t)ob*NP*NE + e;
  float s = 0.f;
  for (int i=0;i<NP;i++) s += p[(size_t)i*NE];
  wsf[WS_M1 + b*NE + e] = s*(1.0f/196.0f);
}

// ---------------- h0/c0 init ----------------
__global__ __launch_bounds__(256) void k_init(const float* __restrict__ ihW, const float* __restrict__ ihb,
                                              const float* __restrict__ icW, const float* __restrict__ icb,
                                              float* __restrict__ wsf){
  int gid = blockIdx.x*256 + threadIdx.x;   // 16384
  int b = gid>>10, x = gid&1023;
  int d = x&511, which = x>>9;
  const float* W = which ? icW : ihW;
  const float* mp = wsf + WS_M1 + b*NE;
  float s = which ? icb[d] : ihb[d];
  for (int e=0;e<NE;e++) s = fmaf(mp[e], W[(size_t)e*ND + d], s);
  wsf[(which?WS_C:WS_H) + b*ND + d] = s;
}

// ---------------- enc transpose to bf16: encT[b][e][p], p padded to 208 ----------------
__global__ __launch_bounds__(256) void k_trans(const float* __restrict__ enc,
                                               const int* __restrict__ wsi,
                                               unsigned short* __restrict__ encT){
  __shared__ float tile[196*65];
  const int tid = threadIdx.x;
  const int b = blockIdx.x >> 4, et = blockIdx.x & 15;
  const int e0 = et*64;
  const int ob = wsi[b];
  for (int idx = tid; idx < 196*16; idx += 256){
    int p = idx >> 4, q = idx & 15;
    float4 v = *(const float4*)(enc + (size_t)ob*NP*NE + (size_t)p*NE + e0 + q*4);
    tile[p*65 + q*4+0] = v.x; tile[p*65 + q*4+1] = v.y;
    tile[p*65 + q*4+2] = v.z; tile[p*65 + q*4+3] = v.w;
  }
  __syncthreads();
  for (int idx = tid; idx < 64*52; idx += 256){
    int el = idx/52, c = idx%52;
    ushort4 o;
    int p = c*4;
    o.x = (p+0<196) ? bf16rne(tile[(p+0)*65 + el]) : (unsigned short)0;
    o.y = (p+1<196) ? bf16rne(tile[(p+1)*65 + el]) : (unsigned short)0;
    o.z = (p+2<196) ? bf16rne(tile[(p+2)*65 + el]) : (unsigned short)0;
    o.w = (p+3<196) ? bf16rne(tile[(p+3)*65 + el]) : (unsigned short)0;
    *(ushort4*)(encT + ((size_t)(b*1024 + e0 + el))*208 + c*4) = o;
  }
}

// ---------------- generic tiled fp32 GEMM (optional bf16 A / bf16 out) ----------------
__global__ __launch_bounds__(256) void k_gemm(const void* __restrict__ Abase,
                                              const float* __restrict__ Bmat,
                                              const float* __restrict__ bias1,
                                              const float* __restrict__ bias2,
                                              void* __restrict__ outv,
                                              int M, int N, int K, int mode,
                                              int abf16, int obf16,
                                              const int* __restrict__ wsi,
                                              const int* __restrict__ caps){
  __shared__ float As[16*64];
  __shared__ float Bs[16*64];
  int tid = threadIdx.x;
  int n0 = blockIdx.x*64, m0 = blockIdx.y*64;
  int tx = tid&15, ty = tid>>4;
  float acc[4][4] = {};
  int r = tid>>2, kq = tid&3;
  int kk = tid>>4, nq = tid&15;
  int row = m0 + r;
  const float* arow = nullptr;
  const unsigned short* arowu = nullptr;
  if (row < M){
    if (mode==0){ int b=row/196, p=row%196; arow = (const float*)Abase + (size_t)(wsi[b]*196 + p)*NE; }
    else if (mode==1){ int t=row>>4, b=row&15; int cap = caps[wsi[b]*NL + t]; arow = (const float*)Abase + (size_t)cap*NEMB; }
    else {
      if (abf16) arowu = (const unsigned short*)Abase + (size_t)row*K;
      else       arow  = (const float*)Abase + (size_t)row*K;
    }
  }
  int ktiles = K>>4;
  for (int kt=0; kt<ktiles; kt++){
    int k0 = kt<<4;
    float4 av = make_float4(0.f,0.f,0.f,0.f);
    if (arow) av = *(const float4*)(arow + k0 + kq*4);
    else if (arowu){
      ushort4 t = *(const ushort4*)(arowu + k0 + kq*4);
      av.x = bf2f(t.x); av.y = bf2f(t.y); av.z = bf2f(t.z); av.w = bf2f(t.w);
    }
    As[(kq*4+0)*64 + r] = av.x;
    As[(kq*4+1)*64 + r] = av.y;
    As[(kq*4+2)*64 + r] = av.z;
    As[(kq*4+3)*64 + r] = av.w;
    int ncol = n0 + nq*4;
    const float* bp = Bmat + (size_t)(k0+kk)*N + ncol;
    float4 bv;
    if (ncol+3 < N) bv = *(const float4*)bp;
    else {
      bv.x = (ncol+0<N)?bp[0]:0.f; bv.y = (ncol+1<N)?bp[1]:0.f;
      bv.z = (ncol+2<N)?bp[2]:0.f; bv.w = (ncol+3<N)?bp[3]:0.f;
    }
    *((float4*)&Bs[kk*64 + nq*4]) = bv;
    __syncthreads();
    #pragma unroll
    for (int k=0;k<16;k++){
      const float4 a = *(const float4*)(&As[k*64 + ty*4]);
      const float4 b = *(const float4*)(&Bs[k*64 + tx*4]);
      float ar[4] = {a.x,a.y,a.z,a.w};
      float br[4] = {b.x,b.y,b.z,b.w};
      #pragma unroll
      for (int i=0;i<4;i++)
        #pragma unroll
        for (int j=0;j<4;j++)
          acc[i][j] = fmaf(ar[i], br[j], acc[i][j]);
    }
    __syncthreads();
  }
  if (mode == 2){
    float* out = (float*)outv;
    #pragma unroll
    for (int i=0;i<4;i++){
      int m = m0 + ty*4 + i;
      if (m >= M) continue;
      int b = m & 15, t = m >> 4;
      bool act = wsi[NB + b] > t;
      size_t obase = (size_t)b*NT*NV + (size_t)t*NV;
      #pragma unroll
      for (int j=0;j<4;j++){
        int n = n0 + tx*4 + j;
        if (n >= N) continue;
        out[obase + n] = act ? (acc[i][j] + bias1[n]) : 0.0f;
      }
    }
  } else {
    #pragma unroll
    for (int i=0;i<4;i++){
      int m = m0 + ty*4 + i;
      if (m >= M) continue;
      #pragma unroll
      for (int j=0;j<4;j++){
        int n = n0 + tx*4 + j;
        if (n >= N) continue;
        float v = acc[i][j] + bias1[n];
        if (bias2) v += bias2[n];
        if (obf16) ((unsigned short*)outv)[(size_t)m*N + n] = bf16rne(v);
        else       ((float*)outv)[(size_t)m*N + n] = v;
      }
    }
  }
}

// ---------------- persistent cooperative scan, 256 blocks x 512 threads ----------------
struct ScanParams {
  float* wsf;
  const int* wsi;
  const unsigned short* att1b;
  const unsigned short* preihb;
  const unsigned short* encT;
  const float* dec_att_W;
  const float* dec_att_b;
  const float* f_beta_W;
  const float* f_beta_b;
  const float* W_hh;
  const float* W_ih;
  const float* full_att_W;
  const float* full_att_b;
  float* out;
};

// custom sense-reversing grid barrier (device-scope atomics, tight spin)
__device__ __forceinline__ void gridbar(unsigned* bar){
  __threadfence();            // all threads: release own writes
  __syncthreads();            // block-wide: fences done
  if (threadIdx.x == 0){
    unsigned g = __hip_atomic_load(&bar[1], __ATOMIC_RELAXED, __HIP_MEMORY_SCOPE_AGENT);
    unsigned a = __hip_atomic_fetch_add(&bar[0], 1u, __ATOMIC_ACQ_REL, __HIP_MEMORY_SCOPE_AGENT);
    if (a == (unsigned)NBLK - 1u){
      __hip_atomic_store(&bar[0], 0u, __ATOMIC_RELAXED, __HIP_MEMORY_SCOPE_AGENT);
      __hip_atomic_fetch_add(&bar[1], 1u, __ATOMIC_RELEASE, __HIP_MEMORY_SCOPE_AGENT);
    } else {
      while (__hip_atomic_load(&bar[1], __ATOMIC_ACQUIRE, __HIP_MEMORY_SCOPE_AGENT) == g)
        __builtin_amdgcn_s_sleep(2);
    }
  }
  __syncthreads();
  __threadfence();            // all threads: acquire
}

__global__ __launch_bounds__(512) void k_scan(ScanParams P){
  __shared__ __align__(16) float lds[12480];
  float* hs      = lds;            // 4*520
  float* cs      = lds + 2080;     // 4*520
  float* sfaW    = lds + 4160;     // 1024 (persistent)
  float* satt2   = lds + 5184;     // 1024 (phase B)
  float* scratch = lds + 6208;     // 6272 (phase A/C/D)

  const int tid = threadIdx.x;
  const int bx = blockIdx.x;           // [0,256)
  const int lane = tid & 63;
  const int wid = tid >> 6;            // [0,8)
  const int bg = bx >> 6;              // 4 batch-groups of 4
  const int jt = bx & 63;              // 64 column tiles
  const bool leader = (jt == 0);

  float* M1     = P.wsf + WS_M1;
  float* gsum   = P.wsf + WS_GSUM;
  float* scores = P.wsf + WS_SCORES;
  unsigned short* aweg_us  = (unsigned short*)(P.wsf + WS_AWEG);
  unsigned short* hhist_us = (unsigned short*)(P.wsf + WS_HHIST);
  unsigned* bar = (unsigned*)(P.wsf) + WS_BAR;
  const int* declen = P.wsi + NB;

  // Phase A tile setup (block-uniform): 64 cols per tile
  const float* Wa; int lda, jbaseA, modeA;
  if (jt < 16){ Wa = P.dec_att_W; lda = 1024; jbaseA = jt*64; modeA = 0; }
  else if (jt < 32){ Wa = P.f_beta_W; lda = 1024; jbaseA = (jt-16)*64; modeA = 1; }
  else { Wa = P.W_hh; lda = 2048; jbaseA = (jt-32)*64; modeA = 2; }
  const float* Wih2 = P.W_ih + (size_t)512*NG;
  const float fab = P.full_att_b[0];

  // persistent full_att_W stage
  for (int x = tid; x < 1024; x += 512) sfaW[x] = P.full_att_W[x];

  for (int tt=0; tt<=NT; tt++){
    // ---- preamble: h(tt), c(tt) into LDS; emit hhist[tt-1] (bf16)
    if (tt == 0){
      const float* h0 = P.wsf + WS_H;
      const float* c0 = P.wsf + WS_C;
      #pragma unroll
      for (int i=0;i<4;i++){
        int idx = tid + i*512;
        int bl = idx >> 9, d = idx & 511;
        int B = bg*4 + bl;
        hs[bl*520 + d] = h0[B*ND + d];
        cs[bl*520 + d] = c0[B*ND + d];
      }
    } else {
      #pragma unroll
      for (int i=0;i<4;i++){
        int idx = tid + i*512;
        int bl = idx >> 9, d = idx & 511;
        int B = bg*4 + bl;
        const float* gp = gsum + B*NG;
        float gi = gp[d], gf = gp[512+d], gG = gp[1024+d], go = gp[1536+d];
        float co = cs[bl*520 + d];
        float cn = sigf(gf)*co + sigf(gi)*tanhf(gG);
        float hn = sigf(go)*tanhf(cn);
        if (leader) hhist_us[((size_t)(tt-1)*NB + B)*ND + d] = bf16rne(hn);
        if (declen[B] > (tt-1)){ hs[bl*520 + d] = hn; cs[bl*520 + d] = cn; }
      }
    }
    __syncthreads();
    if (tt == NT) break;

    // ---- Phase A: M1[B][jout] = h . W (att2 | sigmoided gate | gates_h), fp32 weights (L2-hot)
    {
      const int jq = tid & 15, bl = (tid>>4)&3, kp = tid>>6;
      const float* wp = Wa + (size_t)(kp*64)*lda + jbaseA + jq*4;
      const float* hp = hs + bl*520 + kp*64;
      float4 acc = make_float4(0.f,0.f,0.f,0.f);
      #pragma unroll
      for (int k4=0;k4<16;k4++){
        float4 w0 = *(const float4*)(wp);
        float4 w1 = *(const float4*)(wp + lda);
        float4 w2 = *(const float4*)(wp + 2*lda);
        float4 w3 = *(const float4*)(wp + 3*lda);
        float4 h4 = *(const float4*)(hp);
        hp += 4; wp += 4*(size_t)lda;
        acc.x = fmaf(w0.x,h4.x,acc.x); acc.y = fmaf(w0.y,h4.x,acc.y); acc.z = fmaf(w0.z,h4.x,acc.z); acc.w = fmaf(w0.w,h4.x,acc.w);
        acc.x = fmaf(w1.x,h4.y,acc.x); acc.y = fmaf(w1.y,h4.y,acc.y); acc.z = fmaf(w1.z,h4.y,acc.z); acc.w = fmaf(w1.w,h4.y,acc.w);
        acc.x = fmaf(w2.x,h4.z,acc.x); acc.y = fmaf(w2.y,h4.z,acc.y); acc.z = fmaf(w2.z,h4.z,acc.z); acc.w = fmaf(w2.w,h4.z,acc.w);
        acc.x = fmaf(w3.x,h4.w,acc.x); acc.y = fmaf(w3.y,h4.w,acc.y); acc.z = fmaf(w3.z,h4.w,acc.z); acc.w = fmaf(w3.w,h4.w,acc.w);
      }
      *(float4*)(scratch + kp*260 + (bl*16+jq)*4) = acc;
      __syncthreads();
      if (tid < 256){
        const int bl2 = tid>>6, jl = tid&63;
        float s = 0.f;
        #pragma unroll
        for (int kp2=0;kp2<8;kp2++) s += scratch[kp2*260 + bl2*64 + jl];
        int jcol = jbaseA + jl;
        int jout = jt*64 + jl;
        float v;
        if (modeA==0) v = s + P.dec_att_b[jcol];
        else if (modeA==1) v = sigf(s + P.f_beta_b[jcol]);
        else v = s;
        M1[(bg*4+bl2)*4096 + jout] = v;
      }
      __syncthreads();
    }
    gridbar(bar);

    // ---- Phase B: scores = relu(att1b + att2).faW + fab ; block owns one b, ~13 rows
    {
      const int b = bx >> 4, sidx = bx & 15;
      for (int x = tid; x < 256; x += 512)
        *(float4*)(satt2 + x*4) = *(const float4*)(M1 + b*4096 + x*4);
      __syncthreads();
      const int p0 = sidx*13;
      const int cnt = (sidx==15) ? 1 : 13;
      for (int rr = wid; rr < cnt; rr += 8){
        int p = p0 + rr;
        const unsigned short* a1 = P.att1b + ((size_t)(b*196+p))*1024;
        float s = 0.f;
        #pragma unroll
        for (int i=0;i<2;i++){
          int e = i*512 + lane*8;
          uint4 u = *(const uint4*)(a1 + e);
          float4 t2a = *(const float4*)(satt2 + e);
          float4 t2b = *(const float4*)(satt2 + e + 4);
          float4 wa = *(const float4*)(sfaW + e);
          float4 wb = *(const float4*)(sfaW + e + 4);
          float f0,f1,v;
          u2f2(u.x,f0,f1);
          v = f0 + t2a.x; v = v>0.f?v:0.f; s = fmaf(v, wa.x, s);
          v = f1 + t2a.y; v = v>0.f?v:0.f; s = fmaf(v, wa.y, s);
          u2f2(u.y,f0,f1);
          v = f0 + t2a.z; v = v>0.f?v:0.f; s = fmaf(v, wa.z, s);
          v = f1 + t2a.w; v = v>0.f?v:0.f; s = fmaf(v, wa.w, s);
          u2f2(u.z,f0,f1);
          v = f0 + t2b.x; v = v>0.f?v:0.f; s = fmaf(v, wb.x, s);
          v = f1 + t2b.y; v = v>0.f?v:0.f; s = fmaf(v, wb.y, s);
          u2f2(u.w,f0,f1);
          v = f0 + t2b.z; v = v>0.f?v:0.f; s = fmaf(v, wb.z, s);
          v = f1 + t2b.w; v = v>0.f?v:0.f; s = fmaf(v, wb.w, s);
        }
        #pragma unroll
        for (int off=32; off; off>>=1) s += __shfl_down(s, off, 64);
        if (lane == 0) scores[b*256 + p] = s + fab;
      }
    }
    gridbar(bar);

    // ---- Phase C: redundant softmax + awe chunk (64 e) from encT; aweg bf16
    {
      float* sc   = scratch;            // 208
      float* red2 = scratch + 208;      // 256
      float* redp = scratch + 464;      // 8*68
      const int b = bx >> 4, ch = bx & 15;
      float v = -1e30f;
      if (tid < 196) v = scores[b*256 + tid];
      if (tid < 208) sc[tid] = v;
      if (tid < 256) red2[tid] = v;
      __syncthreads();
      for (int s2=128; s2; s2>>=1){ if (tid < s2) red2[tid] = fmaxf(red2[tid], red2[tid+s2]); __syncthreads(); }
      const float mx = red2[0];
      __syncthreads();
      float ex = (tid < 196) ? expf(sc[tid] - mx) : 0.f;
      if (tid < 208) sc[tid] = ex;
      if (tid < 256) red2[tid] = ex;
      __syncthreads();
      for (int s2=128; s2; s2>>=1){ if (tid < s2) red2[tid] += red2[tid+s2]; __syncthreads(); }
      const float inv = 1.f / red2[0];
      __syncthreads();
      if (tid < 208) sc[tid] *= inv;    // alpha, zero-padded to 208
      __syncthreads();
      const int el = tid & 63, pp = tid >> 6;
      const unsigned* erow = (const unsigned*)P.encT +
          ((((size_t)(b*1024 + ch*64 + el))*208 + pp*26) >> 1);
      float part = 0.f;
      #pragma unroll
      for (int i=0;i<13;i++){
        unsigned u = erow[i];
        float f0,f1; u2f2(u,f0,f1);
        part = fmaf(f0, sc[pp*26 + 2*i],     part);
        part = fmaf(f1, sc[pp*26 + 2*i + 1], part);
      }
      redp[pp*68 + el] = part;
      __syncthreads();
      if (tid < 64){
        float aw = 0.f;
        #pragma unroll
        for (int q=0;q<8;q++) aw += redp[q*68 + tid];
        int e2 = ch*64 + tid;
        aweg_us[b*1024 + e2] = bf16rne(M1[b*4096 + 1024 + e2] + aw);
      }
      if (ch == 0 && tid < 196){
        P.out[OFF_ALPHAS + (size_t)b*NT*NP + (size_t)tt*NP + tid] = (declen[b] > tt) ? sc[tid] : 0.f;
      }
      __syncthreads();
    }
    gridbar(bar);

    // ---- Phase D: gsum[B][j] = preihb + gates_h + aweg . Wih2 (fp32 weights, L2-hot)
    {
      float* ags  = scratch;            // 4*1040
      float* redd = scratch + 4160;     // 16*132
      const int B0 = bg*4;
      #pragma unroll
      for (int i=0;i<4;i++){
        int idx = tid + i*512;          // uint index in [0,2048)
        int bl = idx >> 9, c = idx & 511;
        unsigned u = ((const unsigned*)aweg_us)[(size_t)(B0+bl)*512 + c];
        float f0,f1; u2f2(u,f0,f1);
        ags[bl*1040 + c*2]     = f0;
        ags[bl*1040 + c*2 + 1] = f1;
      }
      __syncthreads();
      const int j0 = jt*32;
      const int jq = tid & 7, bl = (tid>>3)&3, kp = tid>>5;
      const float* wp = Wih2 + (size_t)(kp*64)*NG + j0 + jq*4;
      const float* ap = ags + bl*1040 + kp*64;
      float4 acc = make_float4(0.f,0.f,0.f,0.f);
      #pragma unroll
      for (int k4=0;k4<16;k4++){
        float4 w0 = *(const float4*)(wp);
        float4 w1 = *(const float4*)(wp + NG);
        float4 w2 = *(const float4*)(wp + 2*NG);
        float4 w3 = *(const float4*)(wp + 3*NG);
        float4 a4 = *(const float4*)(ap);
        ap += 4; wp += 4*(size_t)NG;
        acc.x = fmaf(w0.x,a4.x,acc.x); acc.y = fmaf(w0.y,a4.x,acc.y); acc.z = fmaf(w0.z,a4.x,acc.z); acc.w = fmaf(w0.w,a4.x,acc.w);
        acc.x = fmaf(w1.x,a4.y,acc.x); acc.y = fmaf(w1.y,a4.y,acc.y); acc.z = fmaf(w1.z,a4.y,acc.z); acc.w = fmaf(w1.w,a4.y,acc.w);
        acc.x = fmaf(w2.x,a4.z,acc.x); acc.y = fmaf(w2.y,a4.z,acc.y); acc.z = fmaf(w2.z,a4.z,acc.z); acc.w = fmaf(w2.w,a4.z,acc.w);
        acc.x = fmaf(w3.x,a4.w,acc.x); acc.y = fmaf(w3.y,a4.w,acc.y); acc.z = fmaf(w3.z,a4.w,acc.z); acc.w = fmaf(w3.w,a4.w,acc.w);
      }
      *(float4*)(redd + kp*132 + (bl*8+jq)*4) = acc;
      __syncthreads();
      if (tid < 128){
        const int bl2 = tid>>5, jl = tid&31;
        float s = 0.f;
        #pragma unroll
        for (int kp2=0;kp2<16;kp2++) s += redd[kp2*132 + bl2*32 + jl];
        int j = j0 + jl;
        int B = bg*4 + bl2;
        gsum[B*NG + j] = s + bf2f(P.preihb[(size_t)(tt*NB + B)*NG + j]) + M1[B*4096 + 2048 + j];
      }
      __syncthreads();
    }
    gridbar(bar);
  }
}

extern "C" void kernel_launch(void* const* d_in, const int* in_sizes, int n_in,
                              void* d_out, int out_size, void* d_ws, size_t ws_size,
                              hipStream_t stream) {
  const float* encoder_out = (const float*)d_in[0];
  const float* enc_att_W   = (const float*)d_in[1];
  const float* enc_att_b   = (const float*)d_in[2];
  const float* dec_att_W   = (const float*)d_in[3];
  const float* dec_att_b   = (const float*)d_in[4];
  const float* full_att_W  = (const float*)d_in[5];
  const float* full_att_b  = (const float*)d_in[6];
  const float* emb         = (const float*)d_in[7];
  const float* W_ih        = (const float*)d_in[8];
  const float* b_ih        = (const float*)d_in[9];
  const float* W_hh        = (const float*)d_in[10];
  const float* b_hh        = (const float*)d_in[11];
  const float* init_h_W    = (const float*)d_in[12];
  const float* init_h_b    = (const float*)d_in[13];
  const float* init_c_W    = (const float*)d_in[14];
  const float* init_c_b    = (const float*)d_in[15];
  const float* f_beta_W    = (const float*)d_in[16];
  const float* f_beta_b    = (const float*)d_in[17];
  const float* fc_W        = (const float*)d_in[18];
  const float* fc_b        = (const float*)d_in[19];
  const int*   caps        = (const int*)d_in[20];
  const int*   caplen      = (const int*)d_in[21];
  (void)in_sizes; (void)n_in; (void)out_size; (void)ws_size;

  float* out = (float*)d_out;
  float* wsf = (float*)d_ws;
  int*   wsi = (int*)d_ws;
  unsigned short* att1b  = (unsigned short*)(out + OFF_ATT1B);
  unsigned short* preihb = (unsigned short*)(out + OFF_PREIHB);
  unsigned short* encT   = (unsigned short*)(out + OFF_ENCT);

  hipLaunchKernelGGL(k_sort, dim3(1), dim3(64), 0, stream, caplen, caps, wsi, out);
  hipLaunchKernelGGL(k_mean, dim3(64), dim3(256), 0, stream, encoder_out, wsi, wsf);
  hipLaunchKernelGGL(k_init, dim3(64), dim3(256), 0, stream, init_h_W, init_h_b, init_c_W, init_c_b, wsf);
  hipLaunchKernelGGL(k_trans, dim3(256), dim3(256), 0, stream, encoder_out, wsi, encT);
  // att1 (bf16 out) : M=3136, N=1024, K=1024
  hipLaunchKernelGGL(k_gemm, dim3(16,49), dim3(256), 0, stream,
                     (const void*)encoder_out, enc_att_W, enc_att_b, (const float*)nullptr,
                     (void*)att1b, 3136, 1024, 1024, 0, 0, 1, wsi, caps);
  // pre_ih (bf16 out) : M=496, N=2048, K=512
  hipLaunchKernelGGL(k_gemm, dim3(32,8), dim3(256), 0, stream,
                     (const void*)emb, W_ih, b_ih, b_hh,
                     (void*)preihb, 496, 2048, 512, 1, 0, 1, wsi, caps);

  ScanParams sp;
  sp.wsf = wsf; sp.wsi = wsi;
  sp.att1b = att1b; sp.preihb = preihb; sp.encT = encT;
  sp.dec_att_W = dec_att_W; sp.dec_att_b = dec_att_b;
  sp.f_beta_W = f_beta_W; sp.f_beta_b = f_beta_b;
  sp.W_hh = W_hh; sp.W_ih = W_ih;
  sp.full_att_W = full_att_W; sp.full_att_b = full_att_b;
  sp.out = out;
  void* args[] = { &sp };
  hipLaunchCooperativeKernel((void*)k_scan, dim3(NBLK), dim3(512), args, 0, stream);

  // predictions = hhist(bf16) @ fc_W + fc_b (masked) : M=496, N=10000, K=512
  hipLaunchKernelGGL(k_gemm, dim3(157,8), dim3(256), 0, stream,
                     (const void*)(wsf + WS_HHIST), fc_W, fc_b, (const float*)nullptr,
                     (void*)out, 496, 10000, 512, 2, 1, 0, wsi, caps);
}

// Round 5
// 10479.791 us; speedup vs baseline: 1.1978x; 1.1978x over previous
//
#include <hip/hip_runtime.h>
#include <math.h>

// Problem dims
#define NB 16
#define NP 196
#define NE 1024
#define ND 512
#define NEMB 512
#define NV 10000
#define NL 32
#define NT 31
#define NG 2048  // 4*D

#define NBLK 256   // cooperative grid == CU count (proven-safe)

// d_out float offsets (real outputs)
#define OFF_PRED    0
#define OFF_CAPS    4960000
#define OFF_DECLEN  4960512
#define OFF_ALPHAS  4960528
#define OFF_SORTIND 5057744

// d_out-aliased scratch (floats; all dead before fc GEMM overwrites pred region)
#define OFF_ATT1B   0         // ushort[3136*1024]          -> 1,605,632 floats
#define OFF_PREIHB  1605632   // ushort[496*2048]           ->   507,904 floats
#define OFF_ENCT    2113536   // ushort[16*1024*208]        -> 1,703,936 floats (end 3,817,472)

// Workspace offsets (float/uint granularity; total 256,256 floats = 1.03 MB < proven 1.49 MB)
#define WS_LEAF   64         // 32 leaves x 64 uints (cache-line separated)
#define WS_ROOT   2112       // 1 uint (own line)
#define WS_GEN    2176       // 1 uint (own line)
#define WS_H      2304
#define WS_C      10496
#define WS_M1     18688      // [16][4096] fp32: att2 | gateS | gates_h (also k_mean scratch)
#define WS_GSUM   84224      // [16][2048] fp32
#define WS_SCORES 116992     // [16][256] fp32
#define WS_AWEG   121088     // ushort[16*1024] (8192 floats)
#define WS_HHIST  129280     // ushort[31*16*512] (126,976 floats) -> end 256,256

__device__ __forceinline__ float sigf(float x){ return 1.0f/(1.0f+expf(-x)); }
__device__ __forceinline__ unsigned short bf16rne(float x){
  unsigned u = __float_as_uint(x);
  unsigned r = (u + 0x7fffu + ((u>>16)&1u)) >> 16;
  return (unsigned short)r;
}
__device__ __forceinline__ float bf2f(unsigned short h){ return __uint_as_float(((unsigned)h)<<16); }
__device__ __forceinline__ void u2f2(unsigned u, float&a, float&b){
  a = __uint_as_float(u<<16); b = __uint_as_float(u & 0xffff0000u);
}

// ---------------- sort + small outputs + barrier init ----------------
__global__ void k_sort(const int* __restrict__ caplen, const int* __restrict__ caps,
                       int* __restrict__ wsi, float* __restrict__ out){
  __shared__ int sidx[NB];
  int tid = threadIdx.x;
  if (tid == 0){
    int len[NB], idx[NB];
    for (int i=0;i<NB;i++){ len[i]=caplen[i]; idx[i]=i; }
    for (int i=1;i<NB;i++){
      int key=idx[i]; int kl=len[key]; int j=i-1;
      while (j>=0 && len[idx[j]]<kl){ idx[j+1]=idx[j]; j--; }
      idx[j+1]=key;
    }
    for (int b=0;b<NB;b++){
      sidx[b]=idx[b];
      wsi[b]=idx[b];
      int dl = len[idx[b]]-1;
      wsi[NB+b]=dl;
      out[OFF_DECLEN+b]=(float)dl;
      out[OFF_SORTIND+b]=(float)idx[b];
    }
  }
  __syncthreads();
  // zero barrier state [WS_LEAF, WS_GEN+64)
  for (int x = tid; x < 2304-64; x += 64) ((unsigned*)wsi)[WS_LEAF + x] = 0u;
  for (int x=tid; x<NB*NL; x+=blockDim.x){
    int b = x>>5, l = x&31;
    out[OFF_CAPS + x] = (float)caps[sidx[b]*NL + l];
  }
}

// ---------------- mean over P (scratch in WS_M1 region) ----------------
__global__ __launch_bounds__(256) void k_mean(const float* __restrict__ enc,
                                              const int* __restrict__ wsi,
                                              float* __restrict__ wsf){
  int gid = blockIdx.x*256 + threadIdx.x;   // 16384 = 16*1024
  int b = gid>>10, e = gid&1023;
  int ob = wsi[b];
  const float* p = enc + (size_t)ob*NP*NE + e;
  float s = 0.f;
  for (int i=0;i<NP;i++) s += p[(size_t)i*NE];
  wsf[WS_M1 + b*NE + e] = s*(1.0f/196.0f);
}

// ---------------- h0/c0 init ----------------
__global__ __launch_bounds__(256) void k_init(const float* __restrict__ ihW, const float* __restrict__ ihb,
                                              const float* __restrict__ icW, const float* __restrict__ icb,
                                              float* __restrict__ wsf){
  int gid = blockIdx.x*256 + threadIdx.x;   // 16384
  int b = gid>>10, x = gid&1023;
  int d = x&511, which = x>>9;
  const float* W = which ? icW : ihW;
  const float* mp = wsf + WS_M1 + b*NE;
  float s = which ? icb[d] : ihb[d];
  for (int e=0;e<NE;e++) s = fmaf(mp[e], W[(size_t)e*ND + d], s);
  wsf[(which?WS_C:WS_H) + b*ND + d] = s;
}

// ---------------- enc transpose to bf16: encT[b][e][p], p padded to 208 ----------------
__global__ __launch_bounds__(256) void k_trans(const float* __restrict__ enc,
                                               const int* __restrict__ wsi,
                                               unsigned short* __restrict__ encT){
  __shared__ float tile[196*65];
  const int tid = threadIdx.x;
  const int b = blockIdx.x >> 4, et = blockIdx.x & 15;
  const int e0 = et*64;
  const int ob = wsi[b];
  for (int idx = tid; idx < 196*16; idx += 256){
    int p = idx >> 4, q = idx & 15;
    float4 v = *(const float4*)(enc + (size_t)ob*NP*NE + (size_t)p*NE + e0 + q*4);
    tile[p*65 + q*4+0] = v.x; tile[p*65 + q*4+1] = v.y;
    tile[p*65 + q*4+2] = v.z; tile[p*65 + q*4+3] = v.w;
  }
  __syncthreads();
  for (int idx = tid; idx < 64*52; idx += 256){
    int el = idx/52, c = idx%52;
    ushort4 o;
    int p = c*4;
    o.x = (p+0<196) ? bf16rne(tile[(p+0)*65 + el]) : (unsigned short)0;
    o.y = (p+1<196) ? bf16rne(tile[(p+1)*65 + el]) : (unsigned short)0;
    o.z = (p+2<196) ? bf16rne(tile[(p+2)*65 + el]) : (unsigned short)0;
    o.w = (p+3<196) ? bf16rne(tile[(p+3)*65 + el]) : (unsigned short)0;
    *(ushort4*)(encT + ((size_t)(b*1024 + e0 + el))*208 + c*4) = o;
  }
}

// ---------------- generic tiled fp32 GEMM (optional bf16 A / bf16 out) ----------------
__global__ __launch_bounds__(256) void k_gemm(const void* __restrict__ Abase,
                                              const float* __restrict__ Bmat,
                                              const float* __restrict__ bias1,
                                              const float* __restrict__ bias2,
                                              void* __restrict__ outv,
                                              int M, int N, int K, int mode,
                                              int abf16, int obf16,
                                              const int* __restrict__ wsi,
                                              const int* __restrict__ caps){
  __shared__ float As[16*64];
  __shared__ float Bs[16*64];
  int tid = threadIdx.x;
  int n0 = blockIdx.x*64, m0 = blockIdx.y*64;
  int tx = tid&15, ty = tid>>4;
  float acc[4][4] = {};
  int r = tid>>2, kq = tid&3;
  int kk = tid>>4, nq = tid&15;
  int row = m0 + r;
  const float* arow = nullptr;
  const unsigned short* arowu = nullptr;
  if (row < M){
    if (mode==0){ int b=row/196, p=row%196; arow = (const float*)Abase + (size_t)(wsi[b]*196 + p)*NE; }
    else if (mode==1){ int t=row>>4, b=row&15; int cap = caps[wsi[b]*NL + t]; arow = (const float*)Abase + (size_t)cap*NEMB; }
    else {
      if (abf16) arowu = (const unsigned short*)Abase + (size_t)row*K;
      else       arow  = (const float*)Abase + (size_t)row*K;
    }
  }
  int ktiles = K>>4;
  for (int kt=0; kt<ktiles; kt++){
    int k0 = kt<<4;
    float4 av = make_float4(0.f,0.f,0.f,0.f);
    if (arow) av = *(const float4*)(arow + k0 + kq*4);
    else if (arowu){
      ushort4 t = *(const ushort4*)(arowu + k0 + kq*4);
      av.x = bf2f(t.x); av.y = bf2f(t.y); av.z = bf2f(t.z); av.w = bf2f(t.w);
    }
    As[(kq*4+0)*64 + r] = av.x;
    As[(kq*4+1)*64 + r] = av.y;
    As[(kq*4+2)*64 + r] = av.z;
    As[(kq*4+3)*64 + r] = av.w;
    int ncol = n0 + nq*4;
    const float* bp = Bmat + (size_t)(k0+kk)*N + ncol;
    float4 bv;
    if (ncol+3 < N) bv = *(const float4*)bp;
    else {
      bv.x = (ncol+0<N)?bp[0]:0.f; bv.y = (ncol+1<N)?bp[1]:0.f;
      bv.z = (ncol+2<N)?bp[2]:0.f; bv.w = (ncol+3<N)?bp[3]:0.f;
    }
    *((float4*)&Bs[kk*64 + nq*4]) = bv;
    __syncthreads();
    #pragma unroll
    for (int k=0;k<16;k++){
      const float4 a = *(const float4*)(&As[k*64 + ty*4]);
      const float4 b = *(const float4*)(&Bs[k*64 + tx*4]);
      float ar[4] = {a.x,a.y,a.z,a.w};
      float br[4] = {b.x,b.y,b.z,b.w};
      #pragma unroll
      for (int i=0;i<4;i++)
        #pragma unroll
        for (int j=0;j<4;j++)
          acc[i][j] = fmaf(ar[i], br[j], acc[i][j]);
    }
    __syncthreads();
  }
  if (mode == 2){
    float* out = (float*)outv;
    #pragma unroll
    for (int i=0;i<4;i++){
      int m = m0 + ty*4 + i;
      if (m >= M) continue;
      int b = m & 15, t = m >> 4;
      bool act = wsi[NB + b] > t;
      size_t obase = (size_t)b*NT*NV + (size_t)t*NV;
      #pragma unroll
      for (int j=0;j<4;j++){
        int n = n0 + tx*4 + j;
        if (n >= N) continue;
        out[obase + n] = act ? (acc[i][j] + bias1[n]) : 0.0f;
      }
    }
  } else {
    #pragma unroll
    for (int i=0;i<4;i++){
      int m = m0 + ty*4 + i;
      if (m >= M) continue;
      #pragma unroll
      for (int j=0;j<4;j++){
        int n = n0 + tx*4 + j;
        if (n >= N) continue;
        float v = acc[i][j] + bias1[n];
        if (bias2) v += bias2[n];
        if (obf16) ((unsigned short*)outv)[(size_t)m*N + n] = bf16rne(v);
        else       ((float*)outv)[(size_t)m*N + n] = v;
      }
    }
  }
}

// ---------------- persistent cooperative scan, 256 blocks x 512 threads ----------------
struct ScanParams {
  float* wsf;
  const int* wsi;
  const unsigned short* att1b;
  const unsigned short* preihb;
  const unsigned short* encT;
  const float* dec_att_W;
  const float* dec_att_b;
  const float* f_beta_W;
  const float* f_beta_b;
  const float* W_hh;
  const float* W_ih;
  const float* full_att_W;
  const float* full_att_b;
  float* out;
};

// hierarchical grid barrier: 32 leaves (8 blocks each) -> root (32) -> monotonic gen
__device__ __forceinline__ void gridbar(unsigned* leafs, unsigned* root, unsigned* gen,
                                        int bx, unsigned target){
  __threadfence();            // release this block's writes
  __syncthreads();
  if (threadIdx.x == 0){
    unsigned* lf = leafs + (bx & 31)*64;
    unsigned a = __hip_atomic_fetch_add(lf, 1u, __ATOMIC_ACQ_REL, __HIP_MEMORY_SCOPE_AGENT);
    if (a == 7u){
      __hip_atomic_store(lf, 0u, __ATOMIC_RELAXED, __HIP_MEMORY_SCOPE_AGENT);
      unsigned r = __hip_atomic_fetch_add(root, 1u, __ATOMIC_ACQ_REL, __HIP_MEMORY_SCOPE_AGENT);
      if (r == 31u){
        __hip_atomic_store(root, 0u, __ATOMIC_RELAXED, __HIP_MEMORY_SCOPE_AGENT);
        __hip_atomic_fetch_add(gen, 1u, __ATOMIC_RELEASE, __HIP_MEMORY_SCOPE_AGENT);
      }
    }
    int it = 0;
    while ((int)(__hip_atomic_load(gen, __ATOMIC_RELAXED, __HIP_MEMORY_SCOPE_AGENT) - target) < 0){
      if (it < 4)       __builtin_amdgcn_s_sleep(1);
      else if (it < 16) __builtin_amdgcn_s_sleep(8);
      else              __builtin_amdgcn_s_sleep(32);
      ++it;
    }
  }
  __syncthreads();
  __threadfence();            // acquire: drop stale lines
}

__global__ __launch_bounds__(512) void k_scan(ScanParams P){
  __shared__ __align__(16) float lds[10432];
  float* hs      = lds;            // 4*520
  float* cs      = lds + 2080;     // 4*520
  float* scratch = lds + 4160;     // 6272 (phase A/C/D)

  const int tid = threadIdx.x;
  const int bx = blockIdx.x;           // [0,256)
  const int lane = tid & 63;
  const int wid = tid >> 6;            // [0,8)
  const int bg = bx >> 6;              // 4 batch-groups of 4
  const int jt = bx & 63;              // 64 column tiles
  const bool leader = (jt == 0);

  float* M1     = P.wsf + WS_M1;
  float* gsum   = P.wsf + WS_GSUM;
  float* scores = P.wsf + WS_SCORES;
  unsigned short* aweg_us  = (unsigned short*)(P.wsf + WS_AWEG);
  unsigned short* hhist_us = (unsigned short*)(P.wsf + WS_HHIST);
  unsigned* leafs = (unsigned*)(P.wsf) + WS_LEAF;
  unsigned* root  = (unsigned*)(P.wsf) + WS_ROOT;
  unsigned* gen   = (unsigned*)(P.wsf) + WS_GEN;
  const int* declen = P.wsi + NB;
  unsigned target = 0;

  // Phase A tile setup (block-uniform): 64 cols per tile
  const float* Wa; int lda, jbaseA, modeA;
  if (jt < 16){ Wa = P.dec_att_W; lda = 1024; jbaseA = jt*64; modeA = 0; }
  else if (jt < 32){ Wa = P.f_beta_W; lda = 1024; jbaseA = (jt-16)*64; modeA = 1; }
  else { Wa = P.W_hh; lda = 2048; jbaseA = (jt-32)*64; modeA = 2; }
  const float* Wih2 = P.W_ih + (size_t)512*NG;
  const float fab = P.full_att_b[0];

  // persistent full_att_W fragment in registers (lane-sliced)
  float faw[16];
  {
    const float* fw = P.full_att_W + lane*8;
    #pragma unroll
    for (int i=0;i<2;i++){
      float4 x = *(const float4*)(fw + i*512);
      float4 y = *(const float4*)(fw + i*512 + 4);
      faw[i*8+0]=x.x; faw[i*8+1]=x.y; faw[i*8+2]=x.z; faw[i*8+3]=x.w;
      faw[i*8+4]=y.x; faw[i*8+5]=y.y; faw[i*8+6]=y.z; faw[i*8+7]=y.w;
    }
  }

  for (int tt=0; tt<=NT; tt++){
    // ---- preamble: h(tt), c(tt) into LDS; emit hhist[tt-1] (bf16)
    if (tt == 0){
      const float* h0 = P.wsf + WS_H;
      const float* c0 = P.wsf + WS_C;
      #pragma unroll
      for (int i=0;i<4;i++){
        int idx = tid + i*512;
        int bl = idx >> 9, d = idx & 511;
        int B = bg*4 + bl;
        hs[bl*520 + d] = h0[B*ND + d];
        cs[bl*520 + d] = c0[B*ND + d];
      }
    } else {
      #pragma unroll
      for (int i=0;i<4;i++){
        int idx = tid + i*512;
        int bl = idx >> 9, d = idx & 511;
        int B = bg*4 + bl;
        const float* gp = gsum + B*NG;
        float gi = gp[d], gf = gp[512+d], gG = gp[1024+d], go = gp[1536+d];
        float co = cs[bl*520 + d];
        float cn = sigf(gf)*co + sigf(gi)*tanhf(gG);
        float hn = sigf(go)*tanhf(cn);
        if (leader) hhist_us[((size_t)(tt-1)*NB + B)*ND + d] = bf16rne(hn);
        if (declen[B] > (tt-1)){ hs[bl*520 + d] = hn; cs[bl*520 + d] = cn; }
      }
    }
    __syncthreads();
    if (tt == NT) break;

    // ---- Phase A: M1[B][jout] = h . W (att2 | sigmoided gate | gates_h)
    if (declen[bg*4] > tt){   // group has at least one active batch (sorted desc)
      const int jq = tid & 15, bl = (tid>>4)&3, kp = tid>>6;
      const float* wp = Wa + (size_t)(kp*64)*lda + jbaseA + jq*4;
      const float* hp = hs + bl*520 + kp*64;
      float4 acc = make_float4(0.f,0.f,0.f,0.f);
      #pragma unroll
      for (int k4=0;k4<16;k4++){
        float4 w0 = *(const float4*)(wp);
        float4 w1 = *(const float4*)(wp + lda);
        float4 w2 = *(const float4*)(wp + 2*lda);
        float4 w3 = *(const float4*)(wp + 3*lda);
        float4 h4 = *(const float4*)(hp);
        hp += 4; wp += 4*(size_t)lda;
        acc.x = fmaf(w0.x,h4.x,acc.x); acc.y = fmaf(w0.y,h4.x,acc.y); acc.z = fmaf(w0.z,h4.x,acc.z); acc.w = fmaf(w0.w,h4.x,acc.w);
        acc.x = fmaf(w1.x,h4.y,acc.x); acc.y = fmaf(w1.y,h4.y,acc.y); acc.z = fmaf(w1.z,h4.y,acc.z); acc.w = fmaf(w1.w,h4.y,acc.w);
        acc.x = fmaf(w2.x,h4.z,acc.x); acc.y = fmaf(w2.y,h4.z,acc.y); acc.z = fmaf(w2.z,h4.z,acc.z); acc.w = fmaf(w2.w,h4.z,acc.w);
        acc.x = fmaf(w3.x,h4.w,acc.x); acc.y = fmaf(w3.y,h4.w,acc.y); acc.z = fmaf(w3.z,h4.w,acc.z); acc.w = fmaf(w3.w,h4.w,acc.w);
      }
      *(float4*)(scratch + kp*260 + (bl*16+jq)*4) = acc;
      __syncthreads();
      if (tid < 256){
        const int bl2 = tid>>6, jl = tid&63;
        float s = 0.f;
        #pragma unroll
        for (int kp2=0;kp2<8;kp2++) s += scratch[kp2*260 + bl2*64 + jl];
        int jcol = jbaseA + jl;
        int jout = jt*64 + jl;
        float v;
        if (modeA==0) v = s + P.dec_att_b[jcol];
        else if (modeA==1) v = sigf(s + P.f_beta_b[jcol]);
        else v = s;
        M1[(bg*4+bl2)*4096 + jout] = v;
      }
      __syncthreads();
    }
    gridbar(leafs, root, gen, bx, ++target);

    // ---- Phase B: scores = relu(att1b + att2).faw + fab ; registers only
    {
      const int b = bx >> 4, sidx = bx & 15;
      if (declen[b] > tt){
        float a2r[16];
        {
          const float* m1b = M1 + b*4096 + lane*8;
          #pragma unroll
          for (int i=0;i<2;i++){
            float4 x = *(const float4*)(m1b + i*512);
            float4 y = *(const float4*)(m1b + i*512 + 4);
            a2r[i*8+0]=x.x; a2r[i*8+1]=x.y; a2r[i*8+2]=x.z; a2r[i*8+3]=x.w;
            a2r[i*8+4]=y.x; a2r[i*8+5]=y.y; a2r[i*8+6]=y.z; a2r[i*8+7]=y.w;
          }
        }
        const int p0 = sidx*13;
        const int cnt = (sidx==15) ? 1 : 13;
        for (int rr = wid; rr < cnt; rr += 8){
          int p = p0 + rr;
          const unsigned short* a1 = P.att1b + ((size_t)(b*196+p))*1024;
          float s = 0.f;
          #pragma unroll
          for (int i=0;i<2;i++){
            uint4 u = *(const uint4*)(a1 + i*512 + lane*8);
            float f0,f1,v;
            u2f2(u.x,f0,f1);
            v = f0 + a2r[i*8+0]; v = v>0.f?v:0.f; s = fmaf(v, faw[i*8+0], s);
            v = f1 + a2r[i*8+1]; v = v>0.f?v:0.f; s = fmaf(v, faw[i*8+1], s);
            u2f2(u.y,f0,f1);
            v = f0 + a2r[i*8+2]; v = v>0.f?v:0.f; s = fmaf(v, faw[i*8+2], s);
            v = f1 + a2r[i*8+3]; v = v>0.f?v:0.f; s = fmaf(v, faw[i*8+3], s);
            u2f2(u.z,f0,f1);
            v = f0 + a2r[i*8+4]; v = v>0.f?v:0.f; s = fmaf(v, faw[i*8+4], s);
            v = f1 + a2r[i*8+5]; v = v>0.f?v:0.f; s = fmaf(v, faw[i*8+5], s);
            u2f2(u.w,f0,f1);
            v = f0 + a2r[i*8+6]; v = v>0.f?v:0.f; s = fmaf(v, faw[i*8+6], s);
            v = f1 + a2r[i*8+7]; v = v>0.f?v:0.f; s = fmaf(v, faw[i*8+7], s);
          }
          #pragma unroll
          for (int off=32; off; off>>=1) s += __shfl_down(s, off, 64);
          if (lane == 0) scores[b*256 + p] = s + fab;
        }
      }
    }
    gridbar(leafs, root, gen, bx, ++target);

    // ---- Phase C: redundant softmax + awe chunk (64 e) from encT; aweg bf16
    {
      const int b = bx >> 4, ch = bx & 15;
      if (declen[b] <= tt){
        if (ch == 0 && tid < 196)
          P.out[OFF_ALPHAS + (size_t)b*NT*NP + (size_t)tt*NP + tid] = 0.f;
      } else {
        float* sc   = scratch;            // 208
        float* red2 = scratch + 208;      // 256
        float* redp = scratch + 464;      // 8*68
        float v = -1e30f;
        if (tid < 196) v = scores[b*256 + tid];
        if (tid < 208) sc[tid] = v;
        if (tid < 256) red2[tid] = v;
        __syncthreads();
        for (int s2=128; s2; s2>>=1){ if (tid < s2) red2[tid] = fmaxf(red2[tid], red2[tid+s2]); __syncthreads(); }
        const float mx = red2[0];
        __syncthreads();
        float ex = (tid < 196) ? expf(sc[tid] - mx) : 0.f;
        if (tid < 208) sc[tid] = ex;
        if (tid < 256) red2[tid] = ex;
        __syncthreads();
        for (int s2=128; s2; s2>>=1){ if (tid < s2) red2[tid] += red2[tid+s2]; __syncthreads(); }
        const float inv = 1.f / red2[0];
        __syncthreads();
        if (tid < 208) sc[tid] *= inv;    // alpha, zero-padded to 208
        __syncthreads();
        const int el = tid & 63, pp = tid >> 6;
        const unsigned* erow = (const unsigned*)P.encT +
            ((((size_t)(b*1024 + ch*64 + el))*208 + pp*26) >> 1);
        float part = 0.f;
        #pragma unroll
        for (int i=0;i<13;i++){
          unsigned u = erow[i];
          float f0,f1; u2f2(u,f0,f1);
          part = fmaf(f0, sc[pp*26 + 2*i],     part);
          part = fmaf(f1, sc[pp*26 + 2*i + 1], part);
        }
        redp[pp*68 + el] = part;
        __syncthreads();
        if (tid < 64){
          float aw = 0.f;
          #pragma unroll
          for (int q=0;q<8;q++) aw += redp[q*68 + tid];
          int e2 = ch*64 + tid;
          aweg_us[b*1024 + e2] = bf16rne(M1[b*4096 + 1024 + e2] + aw);
        }
        if (ch == 0 && tid < 196){
          P.out[OFF_ALPHAS + (size_t)b*NT*NP + (size_t)tt*NP + tid] = (declen[b] > tt) ? sc[tid] : 0.f;
        }
        __syncthreads();
      }
    }
    gridbar(leafs, root, gen, bx, ++target);

    // ---- Phase D: gsum[B][j] = preihb + gates_h + aweg . Wih2
    if (declen[bg*4] > tt){
      float* ags  = scratch;            // 4*1040
      float* redd = scratch + 4160;     // 16*132
      const int B0 = bg*4;
      #pragma unroll
      for (int i=0;i<4;i++){
        int idx = tid + i*512;          // uint index in [0,2048)
        int bl = idx >> 9, c = idx & 511;
        unsigned u = ((const unsigned*)aweg_us)[(size_t)(B0+bl)*512 + c];
        float f0,f1; u2f2(u,f0,f1);
        ags[bl*1040 + c*2]     = f0;
        ags[bl*1040 + c*2 + 1] = f1;
      }
      __syncthreads();
      const int j0 = jt*32;
      const int jq = tid & 7, bl = (tid>>3)&3, kp = tid>>5;
      const float* wp = Wih2 + (size_t)(kp*64)*NG + j0 + jq*4;
      const float* ap = ags + bl*1040 + kp*64;
      float4 acc = make_float4(0.f,0.f,0.f,0.f);
      #pragma unroll
      for (int k4=0;k4<16;k4++){
        float4 w0 = *(const float4*)(wp);
        float4 w1 = *(const float4*)(wp + NG);
        float4 w2 = *(const float4*)(wp + 2*NG);
        float4 w3 = *(const float4*)(wp + 3*NG);
        float4 a4 = *(const float4*)(ap);
        ap += 4; wp += 4*(size_t)NG;
        acc.x = fmaf(w0.x,a4.x,acc.x); acc.y = fmaf(w0.y,a4.x,acc.y); acc.z = fmaf(w0.z,a4.x,acc.z); acc.w = fmaf(w0.w,a4.x,acc.w);
        acc.x = fmaf(w1.x,a4.y,acc.x); acc.y = fmaf(w1.y,a4.y,acc.y); acc.z = fmaf(w1.z,a4.y,acc.z); acc.w = fmaf(w1.w,a4.y,acc.w);
        acc.x = fmaf(w2.x,a4.z,acc.x); acc.y = fmaf(w2.y,a4.z,acc.y); acc.z = fmaf(w2.z,a4.z,acc.z); acc.w = fmaf(w2.w,a4.z,acc.w);
        acc.x = fmaf(w3.x,a4.w,acc.x); acc.y = fmaf(w3.y,a4.w,acc.y); acc.z = fmaf(w3.z,a4.w,acc.z); acc.w = fmaf(w3.w,a4.w,acc.w);
      }
      *(float4*)(redd + kp*132 + (bl*8+jq)*4) = acc;
      __syncthreads();
      if (tid < 128){
        const int bl2 = tid>>5, jl = tid&31;
        float s = 0.f;
        #pragma unroll
        for (int kp2=0;kp2<16;kp2++) s += redd[kp2*132 + bl2*32 + jl];
        int j = j0 + jl;
        int B = bg*4 + bl2;
        gsum[B*NG + j] = s + bf2f(P.preihb[(size_t)(tt*NB + B)*NG + j]) + M1[B*4096 + 2048 + j];
      }
      __syncthreads();
    }
    gridbar(leafs, root, gen, bx, ++target);
  }
}

extern "C" void kernel_launch(void* const* d_in, const int* in_sizes, int n_in,
                              void* d_out, int out_size, void* d_ws, size_t ws_size,
                              hipStream_t stream) {
  const float* encoder_out = (const float*)d_in[0];
  const float* enc_att_W   = (const float*)d_in[1];
  const float* enc_att_b   = (const float*)d_in[2];
  const float* dec_att_W   = (const float*)d_in[3];
  const float* dec_att_b   = (const float*)d_in[4];
  const float* full_att_W  = (const float*)d_in[5];
  const float* full_att_b  = (const float*)d_in[6];
  const float* emb         = (const float*)d_in[7];
  const float* W_ih        = (const float*)d_in[8];
  const float* b_ih        = (const float*)d_in[9];
  const float* W_hh        = (const float*)d_in[10];
  const float* b_hh        = (const float*)d_in[11];
  const float* init_h_W    = (const float*)d_in[12];
  const float* init_h_b    = (const float*)d_in[13];
  const float* init_c_W    = (const float*)d_in[14];
  const float* init_c_b    = (const float*)d_in[15];
  const float* f_beta_W    = (const float*)d_in[16];
  const float* f_beta_b    = (const float*)d_in[17];
  const float* fc_W        = (const float*)d_in[18];
  const float* fc_b        = (const float*)d_in[19];
  const int*   caps        = (const int*)d_in[20];
  const int*   caplen      = (const int*)d_in[21];
  (void)in_sizes; (void)n_in; (void)out_size; (void)ws_size;

  float* out = (float*)d_out;
  float* wsf = (float*)d_ws;
  int*   wsi = (int*)d_ws;
  unsigned short* att1b  = (unsigned short*)(out + OFF_ATT1B);
  unsigned short* preihb = (unsigned short*)(out + OFF_PREIHB);
  unsigned short* encT   = (unsigned short*)(out + OFF_ENCT);

  hipLaunchKernelGGL(k_sort, dim3(1), dim3(64), 0, stream, caplen, caps, wsi, out);
  hipLaunchKernelGGL(k_mean, dim3(64), dim3(256), 0, stream, encoder_out, wsi, wsf);
  hipLaunchKernelGGL(k_init, dim3(64), dim3(256), 0, stream, init_h_W, init_h_b, init_c_W, init_c_b, wsf);
  hipLaunchKernelGGL(k_trans, dim3(256), dim3(256), 0, stream, encoder_out, wsi, encT);
  // att1 (bf16 out) : M=3136, N=1024, K=1024
  hipLaunchKernelGGL(k_gemm, dim3(16,49), dim3(256), 0, stream,
                     (const void*)encoder_out, enc_att_W, enc_att_b, (const float*)nullptr,
                     (void*)att1b, 3136, 1024, 1024, 0, 0, 1, wsi, caps);
  // pre_ih (bf16 out) : M=496, N=2048, K=512
  hipLaunchKernelGGL(k_gemm, dim3(32,8), dim3(256), 0, stream,
                     (const void*)emb, W_ih, b_ih, b_hh,
                     (void*)preihb, 496, 2048, 512, 1, 0, 1, wsi, caps);

  ScanParams sp;
  sp.wsf = wsf; sp.wsi = wsi;
  sp.att1b = att1b; sp.preihb = preihb; sp.encT = encT;
  sp.dec_att_W = dec_att_W; sp.dec_att_b = dec_att_b;
  sp.f_beta_W = f_beta_W; sp.f_beta_b = f_beta_b;
  sp.W_hh = W_hh; sp.W_ih = W_ih;
  sp.full_att_W = full_att_W; sp.full_att_b = full_att_b;
  sp.out = out;
  void* args[] = { &sp };
  hipLaunchCooperativeKernel((void*)k_scan, dim3(NBLK), dim3(512), args, 0, stream);

  // predictions = hhist(bf16) @ fc_W + fc_b (masked) : M=496, N=10000, K=512
  hipLaunchKernelGGL(k_gemm, dim3(157,8), dim3(256), 0, stream,
                     (const void*)(wsf + WS_HHIST), fc_W, fc_b, (const float*)nullptr,
                     (void*)out, 496, 10000, 512, 2, 1, 0, wsi, caps);
}

// Round 6
// 2375.612 us; speedup vs baseline: 5.2842x; 4.4114x over previous
//
#include <hip/hip_runtime.h>
#include <math.h>

// Problem dims
#define NB 16
#define NP 196
#define NE 1024
#define ND 512
#define NEMB 512
#define NV 10000
#define NL 32
#define NT 31
#define NG 2048  // 4*D

#define NBLK 256   // cooperative grid == CU count (proven-safe)

// d_out float offsets (real outputs)
#define OFF_PRED    0
#define OFF_CAPS    4960000
#define OFF_DECLEN  4960512
#define OFF_ALPHAS  4960528
#define OFF_SORTIND 5057744

// d_out-aliased scratch (floats; all dead before fc GEMM overwrites pred region)
#define OFF_ATT1B   0         // ushort[3136*1024]          -> 1,605,632 floats
#define OFF_PREIHB  1605632   // ushort[496*2048]           ->   507,904 floats
#define OFF_ENCT    2113536   // ushort[16*1024*208]        -> 1,703,936 floats (end 3,817,472)

// Workspace offsets (float granularity; total 231,680 floats = 0.93 MB)
#define WS_LEAF   64         // 32 leaves x 64 uints (cache-line separated)
#define WS_ROOT   2112       // own line
#define WS_GEN    2176       // own line
#define WS_H      2304       // [16][512] fp32  (coherent exchange)
#define WS_C      10496      // [16][512] fp32  (block-private to D owners)
#define WS_M1     18688      // [16][4096] fp32 (coherent): att2 | gateS | gates_h (also k_mean scratch)
#define WS_SCORES 84224      // [16][256] fp32 (coherent)
#define WS_AWEG   88320      // [16][1024] fp32 (coherent)
#define WS_HHIST  104704     // ushort[31*16*512] = 126,976 floats -> end 231,680

__device__ __forceinline__ float sigf(float x){ return 1.0f/(1.0f+expf(-x)); }
__device__ __forceinline__ unsigned short bf16rne(float x){
  unsigned u = __float_as_uint(x);
  unsigned r = (u + 0x7fffu + ((u>>16)&1u)) >> 16;
  return (unsigned short)r;
}
__device__ __forceinline__ float bf2f(unsigned short h){ return __uint_as_float(((unsigned)h)<<16); }
__device__ __forceinline__ void u2f2(unsigned u, float&a, float&b){
  a = __uint_as_float(u<<16); b = __uint_as_float(u & 0xffff0000u);
}
// coherence-point (agent-scope) data exchange: bypasses non-coherent L2, NO cache invalidation
__device__ __forceinline__ void cstore(float* p, float v){
  __hip_atomic_store(p, v, __ATOMIC_RELAXED, __HIP_MEMORY_SCOPE_AGENT);
}
__device__ __forceinline__ float cload(const float* p){
  return __hip_atomic_load(p, __ATOMIC_RELAXED, __HIP_MEMORY_SCOPE_AGENT);
}
__device__ __forceinline__ float2 cload2(const float* p){
  unsigned long long u = __hip_atomic_load((const unsigned long long*)p, __ATOMIC_RELAXED, __HIP_MEMORY_SCOPE_AGENT);
  float2 r; r.x = __uint_as_float((unsigned)u); r.y = __uint_as_float((unsigned)(u>>32));
  return r;
}

// ---------------- sort + small outputs + barrier init ----------------
__global__ void k_sort(const int* __restrict__ caplen, const int* __restrict__ caps,
                       int* __restrict__ wsi, float* __restrict__ out){
  __shared__ int sidx[NB];
  int tid = threadIdx.x;
  if (tid == 0){
    int len[NB], idx[NB];
    for (int i=0;i<NB;i++){ len[i]=caplen[i]; idx[i]=i; }
    for (int i=1;i<NB;i++){
      int key=idx[i]; int kl=len[key]; int j=i-1;
      while (j>=0 && len[idx[j]]<kl){ idx[j+1]=idx[j]; j--; }
      idx[j+1]=key;
    }
    for (int b=0;b<NB;b++){
      sidx[b]=idx[b];
      wsi[b]=idx[b];
      int dl = len[idx[b]]-1;
      wsi[NB+b]=dl;
      out[OFF_DECLEN+b]=(float)dl;
      out[OFF_SORTIND+b]=(float)idx[b];
    }
  }
  __syncthreads();
  // zero barrier state [WS_LEAF, 2304)
  for (int x = tid; x < 2304-64; x += 64) ((unsigned*)wsi)[WS_LEAF + x] = 0u;
  for (int x=tid; x<NB*NL; x+=blockDim.x){
    int b = x>>5, l = x&31;
    out[OFF_CAPS + x] = (float)caps[sidx[b]*NL + l];
  }
}

// ---------------- mean over P (scratch in WS_M1 region) ----------------
__global__ __launch_bounds__(256) void k_mean(const float* __restrict__ enc,
                                              const int* __restrict__ wsi,
                                              float* __restrict__ wsf){
  int gid = blockIdx.x*256 + threadIdx.x;   // 16384 = 16*1024
  int b = gid>>10, e = gid&1023;
  int ob = wsi[b];
  const float* p = enc + (size_t)ob*NP*NE + e;
  float s = 0.f;
  for (int i=0;i<NP;i++) s += p[(size_t)i*NE];
  wsf[WS_M1 + b*NE + e] = s*(1.0f/196.0f);
}

// ---------------- h0/c0 init ----------------
__global__ __launch_bounds__(256) void k_init(const float* __restrict__ ihW, const float* __restrict__ ihb,
                                              const float* __restrict__ icW, const float* __restrict__ icb,
                                              float* __restrict__ wsf){
  int gid = blockIdx.x*256 + threadIdx.x;   // 16384
  int b = gid>>10, x = gid&1023;
  int d = x&511, which = x>>9;
  const float* W = which ? icW : ihW;
  const float* mp = wsf + WS_M1 + b*NE;
  float s = which ? icb[d] : ihb[d];
  for (int e=0;e<NE;e++) s = fmaf(mp[e], W[(size_t)e*ND + d], s);
  wsf[(which?WS_C:WS_H) + b*ND + d] = s;
}

// ---------------- enc transpose to bf16: encT[b][e][p], p padded to 208 ----------------
__global__ __launch_bounds__(256) void k_trans(const float* __restrict__ enc,
                                               const int* __restrict__ wsi,
                                               unsigned short* __restrict__ encT){
  __shared__ float tile[196*65];
  const int tid = threadIdx.x;
  const int b = blockIdx.x >> 4, et = blockIdx.x & 15;
  const int e0 = et*64;
  const int ob = wsi[b];
  for (int idx = tid; idx < 196*16; idx += 256){
    int p = idx >> 4, q = idx & 15;
    float4 v = *(const float4*)(enc + (size_t)ob*NP*NE + (size_t)p*NE + e0 + q*4);
    tile[p*65 + q*4+0] = v.x; tile[p*65 + q*4+1] = v.y;
    tile[p*65 + q*4+2] = v.z; tile[p*65 + q*4+3] = v.w;
  }
  __syncthreads();
  for (int idx = tid; idx < 64*52; idx += 256){
    int el = idx/52, c = idx%52;
    ushort4 o;
    int p = c*4;
    o.x = (p+0<196) ? bf16rne(tile[(p+0)*65 + el]) : (unsigned short)0;
    o.y = (p+1<196) ? bf16rne(tile[(p+1)*65 + el]) : (unsigned short)0;
    o.z = (p+2<196) ? bf16rne(tile[(p+2)*65 + el]) : (unsigned short)0;
    o.w = (p+3<196) ? bf16rne(tile[(p+3)*65 + el]) : (unsigned short)0;
    *(ushort4*)(encT + ((size_t)(b*1024 + e0 + el))*208 + c*4) = o;
  }
}

// ---------------- generic tiled fp32 GEMM (optional bf16 A / bf16 out) ----------------
__global__ __launch_bounds__(256) void k_gemm(const void* __restrict__ Abase,
                                              const float* __restrict__ Bmat,
                                              const float* __restrict__ bias1,
                                              const float* __restrict__ bias2,
                                              void* __restrict__ outv,
                                              int M, int N, int K, int mode,
                                              int abf16, int obf16,
                                              const int* __restrict__ wsi,
                                              const int* __restrict__ caps){
  __shared__ float As[16*64];
  __shared__ float Bs[16*64];
  int tid = threadIdx.x;
  int n0 = blockIdx.x*64, m0 = blockIdx.y*64;
  int tx = tid&15, ty = tid>>4;
  float acc[4][4] = {};
  int r = tid>>2, kq = tid&3;
  int kk = tid>>4, nq = tid&15;
  int row = m0 + r;
  const float* arow = nullptr;
  const unsigned short* arowu = nullptr;
  if (row < M){
    if (mode==0){ int b=row/196, p=row%196; arow = (const float*)Abase + (size_t)(wsi[b]*196 + p)*NE; }
    else if (mode==1){ int t=row>>4, b=row&15; int cap = caps[wsi[b]*NL + t]; arow = (const float*)Abase + (size_t)cap*NEMB; }
    else {
      if (abf16) arowu = (const unsigned short*)Abase + (size_t)row*K;
      else       arow  = (const float*)Abase + (size_t)row*K;
    }
  }
  int ktiles = K>>4;
  for (int kt=0; kt<ktiles; kt++){
    int k0 = kt<<4;
    float4 av = make_float4(0.f,0.f,0.f,0.f);
    if (arow) av = *(const float4*)(arow + k0 + kq*4);
    else if (arowu){
      ushort4 t = *(const ushort4*)(arowu + k0 + kq*4);
      av.x = bf2f(t.x); av.y = bf2f(t.y); av.z = bf2f(t.z); av.w = bf2f(t.w);
    }
    As[(kq*4+0)*64 + r] = av.x;
    As[(kq*4+1)*64 + r] = av.y;
    As[(kq*4+2)*64 + r] = av.z;
    As[(kq*4+3)*64 + r] = av.w;
    int ncol = n0 + nq*4;
    const float* bp = Bmat + (size_t)(k0+kk)*N + ncol;
    float4 bv;
    if (ncol+3 < N) bv = *(const float4*)bp;
    else {
      bv.x = (ncol+0<N)?bp[0]:0.f; bv.y = (ncol+1<N)?bp[1]:0.f;
      bv.z = (ncol+2<N)?bp[2]:0.f; bv.w = (ncol+3<N)?bp[3]:0.f;
    }
    *((float4*)&Bs[kk*64 + nq*4]) = bv;
    __syncthreads();
    #pragma unroll
    for (int k=0;k<16;k++){
      const float4 a = *(const float4*)(&As[k*64 + ty*4]);
      const float4 b = *(const float4*)(&Bs[k*64 + tx*4]);
      float ar[4] = {a.x,a.y,a.z,a.w};
      float br[4] = {b.x,b.y,b.z,b.w};
      #pragma unroll
      for (int i=0;i<4;i++)
        #pragma unroll
        for (int j=0;j<4;j++)
          acc[i][j] = fmaf(ar[i], br[j], acc[i][j]);
    }
    __syncthreads();
  }
  if (mode == 2){
    float* out = (float*)outv;
    #pragma unroll
    for (int i=0;i<4;i++){
      int m = m0 + ty*4 + i;
      if (m >= M) continue;
      int b = m & 15, t = m >> 4;
      bool act = wsi[NB + b] > t;
      size_t obase = (size_t)b*NT*NV + (size_t)t*NV;
      #pragma unroll
      for (int j=0;j<4;j++){
        int n = n0 + tx*4 + j;
        if (n >= N) continue;
        out[obase + n] = act ? (acc[i][j] + bias1[n]) : 0.0f;
      }
    }
  } else {
    #pragma unroll
    for (int i=0;i<4;i++){
      int m = m0 + ty*4 + i;
      if (m >= M) continue;
      #pragma unroll
      for (int j=0;j<4;j++){
        int n = n0 + tx*4 + j;
        if (n >= N) continue;
        float v = acc[i][j] + bias1[n];
        if (bias2) v += bias2[n];
        if (obf16) ((unsigned short*)outv)[(size_t)m*N + n] = bf16rne(v);
        else       ((float*)outv)[(size_t)m*N + n] = v;
      }
    }
  }
}

// ---------------- persistent cooperative scan, 256 blocks x 512 threads ----------------
struct ScanParams {
  float* wsf;
  const int* wsi;
  const unsigned short* att1b;
  const unsigned short* preihb;
  const unsigned short* encT;
  const float* dec_att_W;
  const float* dec_att_b;
  const float* f_beta_W;
  const float* f_beta_b;
  const float* W_hh;
  const float* W_ih;
  const float* full_att_W;
  const float* full_att_b;
  float* out;
};

// FENCE-FREE hierarchical barrier. No __threadfence => L2 never invalidated.
// Correctness: all cross-block data uses agent-scope atomics (coherence point);
// release RMW on arrival orders those stores before the gen bump.
__device__ __forceinline__ void gridbar(unsigned* leafs, unsigned* root, unsigned* gen,
                                        int bx, unsigned target){
  __syncthreads();
  if (threadIdx.x == 0){
    unsigned* lf = leafs + (bx & 31)*64;
    unsigned a = __hip_atomic_fetch_add(lf, 1u, __ATOMIC_RELEASE, __HIP_MEMORY_SCOPE_AGENT);
    if (a == 7u){
      __hip_atomic_store(lf, 0u, __ATOMIC_RELAXED, __HIP_MEMORY_SCOPE_AGENT);
      unsigned r = __hip_atomic_fetch_add(root, 1u, __ATOMIC_RELEASE, __HIP_MEMORY_SCOPE_AGENT);
      if (r == 31u){
        __hip_atomic_store(root, 0u, __ATOMIC_RELAXED, __HIP_MEMORY_SCOPE_AGENT);
        __hip_atomic_fetch_add(gen, 1u, __ATOMIC_RELEASE, __HIP_MEMORY_SCOPE_AGENT);
      }
    }
    while ((int)(__hip_atomic_load(gen, __ATOMIC_RELAXED, __HIP_MEMORY_SCOPE_AGENT) - target) < 0)
      __builtin_amdgcn_s_sleep(1);
  }
  __syncthreads();
  __asm__ volatile("" ::: "memory");
}

__global__ __launch_bounds__(512) void k_scan(ScanParams P){
  __shared__ __align__(16) float lds[8480];
  float* hs      = lds;            // 4*520
  float* scratch = lds + 2080;     // 6400: A(2080) / C(1008) / D(ags 4160 + redd 2112 + gl 128)

  const int tid = threadIdx.x;
  const int bx = blockIdx.x;           // [0,256)
  const int lane = tid & 63;
  const int wid = tid >> 6;            // [0,8)
  const int bg = bx >> 6;              // 4 batch-groups of 4
  const int jt = bx & 63;              // 64 column tiles

  float* M1     = P.wsf + WS_M1;
  float* hws    = P.wsf + WS_H;
  float* cws    = P.wsf + WS_C;
  float* scores = P.wsf + WS_SCORES;
  float* aweg   = P.wsf + WS_AWEG;
  unsigned short* hhist_us = (unsigned short*)(P.wsf + WS_HHIST);
  unsigned* leafs = (unsigned*)(P.wsf) + WS_LEAF;
  unsigned* root  = (unsigned*)(P.wsf) + WS_ROOT;
  unsigned* gen   = (unsigned*)(P.wsf) + WS_GEN;
  const int* declen = P.wsi + NB;
  unsigned target = 0;

  // Phase A tile setup (block-uniform): 64 cols per tile
  const float* Wa; int lda, jbaseA, modeA;
  if (jt < 16){ Wa = P.dec_att_W; lda = 1024; jbaseA = jt*64; modeA = 0; }
  else if (jt < 32){ Wa = P.f_beta_W; lda = 1024; jbaseA = (jt-16)*64; modeA = 1; }
  else { Wa = P.W_hh; lda = 2048; jbaseA = (jt-32)*64; modeA = 2; }
  const float* Wih2 = P.W_ih + (size_t)512*NG;
  const float fab = P.full_att_b[0];
  const int d0 = jt*8;              // D-phase d-slice ownership

  // persistent full_att_W fragment in registers (lane-sliced)
  float faw[16];
  {
    const float* fw = P.full_att_W + lane*8;
    #pragma unroll
    for (int i=0;i<2;i++){
      float4 x = *(const float4*)(fw + i*512);
      float4 y = *(const float4*)(fw + i*512 + 4);
      faw[i*8+0]=x.x; faw[i*8+1]=x.y; faw[i*8+2]=x.z; faw[i*8+3]=x.w;
      faw[i*8+4]=y.x; faw[i*8+5]=y.y; faw[i*8+6]=y.z; faw[i*8+7]=y.w;
    }
  }

  for (int tt=0; tt<NT; tt++){
    // ---- preamble: load h(tt) into LDS (coherent — written by D / k_init)
    #pragma unroll
    for (int i=0;i<2;i++){
      int idx = tid + i*512;           // float2 units [0,1024)
      int bl = idx >> 8, dp = idx & 255;
      float2 v = cload2(hws + (size_t)(bg*4+bl)*ND + dp*2);
      hs[bl*520 + dp*2]   = v.x;
      hs[bl*520 + dp*2+1] = v.y;
    }
    __syncthreads();

    // ---- Phase A: M1[B][jout] = h . W (att2 | sigmoided gate | gates_h)
    if (declen[bg*4] > tt){   // group active (sorted desc)
      const int jq = tid & 15, bl = (tid>>4)&3, kp = tid>>6;
      const float* wp = Wa + (size_t)(kp*64)*lda + jbaseA + jq*4;
      const float* hp = hs + bl*520 + kp*64;
      float4 acc = make_float4(0.f,0.f,0.f,0.f);
      #pragma unroll
      for (int k4=0;k4<16;k4++){
        float4 w0 = *(const float4*)(wp);
        float4 w1 = *(const float4*)(wp + lda);
        float4 w2 = *(const float4*)(wp + 2*lda);
        float4 w3 = *(const float4*)(wp + 3*lda);
        float4 h4 = *(const float4*)(hp);
        hp += 4; wp += 4*(size_t)lda;
        acc.x = fmaf(w0.x,h4.x,acc.x); acc.y = fmaf(w0.y,h4.x,acc.y); acc.z = fmaf(w0.z,h4.x,acc.z); acc.w = fmaf(w0.w,h4.x,acc.w);
        acc.x = fmaf(w1.x,h4.y,acc.x); acc.y = fmaf(w1.y,h4.y,acc.y); acc.z = fmaf(w1.z,h4.y,acc.z); acc.w = fmaf(w1.w,h4.y,acc.w);
        acc.x = fmaf(w2.x,h4.z,acc.x); acc.y = fmaf(w2.y,h4.z,acc.y); acc.z = fmaf(w2.z,h4.z,acc.z); acc.w = fmaf(w2.w,h4.z,acc.w);
        acc.x = fmaf(w3.x,h4.w,acc.x); acc.y = fmaf(w3.y,h4.w,acc.y); acc.z = fmaf(w3.z,h4.w,acc.z); acc.w = fmaf(w3.w,h4.w,acc.w);
      }
      *(float4*)(scratch + kp*260 + (bl*16+jq)*4) = acc;
      __syncthreads();
      if (tid < 256){
        const int bl2 = tid>>6, jl = tid&63;
        float s = 0.f;
        #pragma unroll
        for (int kp2=0;kp2<8;kp2++) s += scratch[kp2*260 + bl2*64 + jl];
        int jcol = jbaseA + jl;
        int jout = jt*64 + jl;
        float v;
        if (modeA==0) v = s + P.dec_att_b[jcol];
        else if (modeA==1) v = sigf(s + P.f_beta_b[jcol]);
        else v = s;
        cstore(&M1[(bg*4+bl2)*4096 + jout], v);
      }
      __syncthreads();
    }
    gridbar(leafs, root, gen, bx, ++target);

    // ---- Phase B: scores = relu(att1b + att2).faw + fab
    {
      const int b = bx >> 4, sidx = bx & 15;
      if (declen[b] > tt){
        float a2r[16];
        {
          const float* m1b = M1 + b*4096 + lane*8;
          #pragma unroll
          for (int i=0;i<2;i++){
            #pragma unroll
            for (int q=0;q<4;q++){
              float2 t = cload2(m1b + i*512 + q*2);
              a2r[i*8+q*2]   = t.x;
              a2r[i*8+q*2+1] = t.y;
            }
          }
        }
        const int p0 = sidx*13;
        const int cnt = (sidx==15) ? 1 : 13;
        for (int rr = wid; rr < cnt; rr += 8){
          int p = p0 + rr;
          const unsigned short* a1 = P.att1b + ((size_t)(b*196+p))*1024;
          float s = 0.f;
          #pragma unroll
          for (int i=0;i<2;i++){
            uint4 u = *(const uint4*)(a1 + i*512 + lane*8);
            float f0,f1,v;
            u2f2(u.x,f0,f1);
            v = f0 + a2r[i*8+0]; v = v>0.f?v:0.f; s = fmaf(v, faw[i*8+0], s);
            v = f1 + a2r[i*8+1]; v = v>0.f?v:0.f; s = fmaf(v, faw[i*8+1], s);
            u2f2(u.y,f0,f1);
            v = f0 + a2r[i*8+2]; v = v>0.f?v:0.f; s = fmaf(v, faw[i*8+2], s);
            v = f1 + a2r[i*8+3]; v = v>0.f?v:0.f; s = fmaf(v, faw[i*8+3], s);
            u2f2(u.z,f0,f1);
            v = f0 + a2r[i*8+4]; v = v>0.f?v:0.f; s = fmaf(v, faw[i*8+4], s);
            v = f1 + a2r[i*8+5]; v = v>0.f?v:0.f; s = fmaf(v, faw[i*8+5], s);
            u2f2(u.w,f0,f1);
            v = f0 + a2r[i*8+6]; v = v>0.f?v:0.f; s = fmaf(v, faw[i*8+6], s);
            v = f1 + a2r[i*8+7]; v = v>0.f?v:0.f; s = fmaf(v, faw[i*8+7], s);
          }
          #pragma unroll
          for (int off=32; off; off>>=1) s += __shfl_down(s, off, 64);
          if (lane == 0) cstore(&scores[b*256 + p], s + fab);
        }
      }
    }
    gridbar(leafs, root, gen, bx, ++target);

    // ---- Phase C: redundant softmax + awe chunk (64 e) from encT; aweg coherent
    {
      const int b = bx >> 4, ch = bx & 15;
      if (declen[b] <= tt){
        if (ch == 0 && tid < 196)
          P.out[OFF_ALPHAS + (size_t)b*NT*NP + (size_t)tt*NP + tid] = 0.f;
      } else {
        float* sc   = scratch;            // 208
        float* red2 = scratch + 208;      // 256
        float* redp = scratch + 464;      // 8*68
        float v = (tid < 196) ? cload(&scores[b*256 + tid]) : -1e30f;
        if (tid < 208) sc[tid] = v;
        if (tid < 256) red2[tid] = v;
        __syncthreads();
        for (int s2=128; s2; s2>>=1){ if (tid < s2) red2[tid] = fmaxf(red2[tid], red2[tid+s2]); __syncthreads(); }
        const float mx = red2[0];
        __syncthreads();
        float ex = (tid < 196) ? expf(sc[tid] - mx) : 0.f;
        if (tid < 208) sc[tid] = ex;
        if (tid < 256) red2[tid] = ex;
        __syncthreads();
        for (int s2=128; s2; s2>>=1){ if (tid < s2) red2[tid] += red2[tid+s2]; __syncthreads(); }
        const float inv = 1.f / red2[0];
        __syncthreads();
        if (tid < 208) sc[tid] *= inv;    // alpha, zero-padded to 208
        __syncthreads();
        const int el = tid & 63, pp = tid >> 6;
        const unsigned* erow = (const unsigned*)P.encT +
            ((((size_t)(b*1024 + ch*64 + el))*208 + pp*26) >> 1);
        float part = 0.f;
        #pragma unroll
        for (int i=0;i<13;i++){
          unsigned u = erow[i];
          float f0,f1; u2f2(u,f0,f1);
          part = fmaf(f0, sc[pp*26 + 2*i],     part);
          part = fmaf(f1, sc[pp*26 + 2*i + 1], part);
        }
        redp[pp*68 + el] = part;
        __syncthreads();
        if (tid < 64){
          float aw = 0.f;
          #pragma unroll
          for (int q=0;q<8;q++) aw += redp[q*68 + tid];
          int e2 = ch*64 + tid;
          cstore(&aweg[b*1024 + e2], cload(&M1[b*4096 + 1024 + e2]) + aw);
        }
        if (ch == 0 && tid < 196){
          P.out[OFF_ALPHAS + (size_t)b*NT*NP + (size_t)tt*NP + tid] = sc[tid];
        }
        __syncthreads();
      }
    }
    gridbar(leafs, root, gen, bx, ++target);

    // ---- Phase D: gates for d-slice [d0,d0+8) x 4 gates + fused LSTM pointwise
    if (declen[bg*4] > tt){
      float* ags  = scratch;            // 4*1040
      float* redd = scratch + 4160;     // 16*132
      float* gl   = scratch + 6272;     // 128
      const int B0 = bg*4;
      #pragma unroll
      for (int i=0;i<4;i++){
        int idx = tid + i*512;          // float2 units [0,2048)
        int bl = idx >> 9, c2 = idx & 511;
        float2 v = cload2(aweg + (size_t)(B0+bl)*1024 + c2*2);
        ags[bl*1040 + c2*2]   = v.x;
        ags[bl*1040 + c2*2+1] = v.y;
      }
      __syncthreads();
      const int jq = tid & 7, bl = (tid>>3)&3, kp = tid>>5;
      const int gate = jq>>1, dq = jq&1;
      const float* wp = Wih2 + (size_t)(kp*64)*NG + gate*512 + d0 + dq*4;
      const float* ap = ags + bl*1040 + kp*64;
      float4 acc = make_float4(0.f,0.f,0.f,0.f);
      #pragma unroll
      for (int k4=0;k4<16;k4++){
        float4 w0 = *(const float4*)(wp);
        float4 w1 = *(const float4*)(wp + NG);
        float4 w2 = *(const float4*)(wp + 2*NG);
        float4 w3 = *(const float4*)(wp + 3*NG);
        float4 a4 = *(const float4*)(ap);
        ap += 4; wp += 4*(size_t)NG;
        acc.x = fmaf(w0.x,a4.x,acc.x); acc.y = fmaf(w0.y,a4.x,acc.y); acc.z = fmaf(w0.z,a4.x,acc.z); acc.w = fmaf(w0.w,a4.x,acc.w);
        acc.x = fmaf(w1.x,a4.y,acc.x); acc.y = fmaf(w1.y,a4.y,acc.y); acc.z = fmaf(w1.z,a4.y,acc.z); acc.w = fmaf(w1.w,a4.y,acc.w);
        acc.x = fmaf(w2.x,a4.z,acc.x); acc.y = fmaf(w2.y,a4.z,acc.y); acc.z = fmaf(w2.z,a4.z,acc.z); acc.w = fmaf(w2.w,a4.z,acc.w);
        acc.x = fmaf(w3.x,a4.w,acc.x); acc.y = fmaf(w3.y,a4.w,acc.y); acc.z = fmaf(w3.z,a4.w,acc.z); acc.w = fmaf(w3.w,a4.w,acc.w);
      }
      *(float4*)(redd + kp*132 + (bl*8+jq)*4) = acc;
      __syncthreads();
      if (tid < 128){
        const int bl2 = tid>>5, jl = tid&31;
        float s = 0.f;
        #pragma unroll
        for (int kp2=0;kp2<16;kp2++) s += redd[kp2*132 + bl2*32 + jl];
        const int jq2 = jl>>2, cc = jl&3;
        const int g2 = jq2>>1, dd = (jq2&1)*4 + cc;
        const int j = g2*512 + d0 + dd;
        const int B = B0 + bl2;
        float gv = s + bf2f(P.preihb[(size_t)(tt*NB + B)*NG + j]) + cload(&M1[B*4096 + 2048 + j]);
        gl[bl2*32 + dd*4 + g2] = gv;
      }
      __syncthreads();
      if (tid < 32){
        const int bi = tid>>3, dd = tid&7;
        const int B = B0 + bi, d = d0 + dd;
        const float gI = gl[bi*32 + dd*4 + 0];
        const float gF = gl[bi*32 + dd*4 + 1];
        const float gG = gl[bi*32 + dd*4 + 2];
        const float gO = gl[bi*32 + dd*4 + 3];
        const float co = cws[B*ND + d];          // block-private (same owner every step)
        const float cn = sigf(gF)*co + sigf(gI)*tanhf(gG);
        const float hn = sigf(gO)*tanhf(cn);
        hhist_us[((size_t)tt*NB + B)*ND + d] = bf16rne(hn);
        if (declen[B] > tt){
          cstore(&hws[B*ND + d], hn);            // broadcast h coherently
          cws[B*ND + d] = cn;
        }
      }
      __syncthreads();
    }
    gridbar(leafs, root, gen, bx, ++target);
  }
}

extern "C" void kernel_launch(void* const* d_in, const int* in_sizes, int n_in,
                              void* d_out, int out_size, void* d_ws, size_t ws_size,
                              hipStream_t stream) {
  const float* encoder_out = (const float*)d_in[0];
  const float* enc_att_W   = (const float*)d_in[1];
  const float* enc_att_b   = (const float*)d_in[2];
  const float* dec_att_W   = (const float*)d_in[3];
  const float* dec_att_b   = (const float*)d_in[4];
  const float* full_att_W  = (const float*)d_in[5];
  const float* full_att_b  = (const float*)d_in[6];
  const float* emb         = (const float*)d_in[7];
  const float* W_ih        = (const float*)d_in[8];
  const float* b_ih        = (const float*)d_in[9];
  const float* W_hh        = (const float*)d_in[10];
  const float* b_hh        = (const float*)d_in[11];
  const float* init_h_W    = (const float*)d_in[12];
  const float* init_h_b    = (const float*)d_in[13];
  const float* init_c_W    = (const float*)d_in[14];
  const float* init_c_b    = (const float*)d_in[15];
  const float* f_beta_W    = (const float*)d_in[16];
  const float* f_beta_b    = (const float*)d_in[17];
  const float* fc_W        = (const float*)d_in[18];
  const float* fc_b        = (const float*)d_in[19];
  const int*   caps        = (const int*)d_in[20];
  const int*   caplen      = (const int*)d_in[21];
  (void)in_sizes; (void)n_in; (void)out_size; (void)ws_size;

  float* out = (float*)d_out;
  float* wsf = (float*)d_ws;
  int*   wsi = (int*)d_ws;
  unsigned short* att1b  = (unsigned short*)(out + OFF_ATT1B);
  unsigned short* preihb = (unsigned short*)(out + OFF_PREIHB);
  unsigned short* encT   = (unsigned short*)(out + OFF_ENCT);

  hipLaunchKernelGGL(k_sort, dim3(1), dim3(64), 0, stream, caplen, caps, wsi, out);
  hipLaunchKernelGGL(k_mean, dim3(64), dim3(256), 0, stream, encoder_out, wsi, wsf);
  hipLaunchKernelGGL(k_init, dim3(64), dim3(256), 0, stream, init_h_W, init_h_b, init_c_W, init_c_b, wsf);
  hipLaunchKernelGGL(k_trans, dim3(256), dim3(256), 0, stream, encoder_out, wsi, encT);
  // att1 (bf16 out) : M=3136, N=1024, K=1024
  hipLaunchKernelGGL(k_gemm, dim3(16,49), dim3(256), 0, stream,
                     (const void*)encoder_out, enc_att_W, enc_att_b, (const float*)nullptr,
                     (void*)att1b, 3136, 1024, 1024, 0, 0, 1, wsi, caps);
  // pre_ih (bf16 out) : M=496, N=2048, K=512
  hipLaunchKernelGGL(k_gemm, dim3(32,8), dim3(256), 0, stream,
                     (const void*)emb, W_ih, b_ih, b_hh,
                     (void*)preihb, 496, 2048, 512, 1, 0, 1, wsi, caps);

  ScanParams sp;
  sp.wsf = wsf; sp.wsi = wsi;
  sp.att1b = att1b; sp.preihb = preihb; sp.encT = encT;
  sp.dec_att_W = dec_att_W; sp.dec_att_b = dec_att_b;
  sp.f_beta_W = f_beta_W; sp.f_beta_b = f_beta_b;
  sp.W_hh = W_hh; sp.W_ih = W_ih;
  sp.full_att_W = full_att_W; sp.full_att_b = full_att_b;
  sp.out = out;
  void* args[] = { &sp };
  hipLaunchCooperativeKernel((void*)k_scan, dim3(NBLK), dim3(512), args, 0, stream);

  // predictions = hhist(bf16) @ fc_W + fc_b (masked) : M=496, N=10000, K=512
  hipLaunchKernelGGL(k_gemm, dim3(157,8), dim3(256), 0, stream,
                     (const void*)(wsf + WS_HHIST), fc_W, fc_b, (const float*)nullptr,
                     (void*)out, 496, 10000, 512, 2, 1, 0, wsi, caps);
}